// Round 3
// baseline (568.115 us; speedup 1.0000x reference)
//
#include <hip/hip_runtime.h>
#include <hip/hip_bf16.h>
#include <math.h>

#define B_ 64
#define M_ 128
#define DMODEL 1024
#define DADDR 64
#define DMEM 128
#define H_ 8
#define EPSF 1e-5f

__device__ __forceinline__ float softplusf(float x) {
    // jax.nn.softplus = log1p(exp(x)) computed as max(x,0)+log1p(exp(-|x|))
    return fmaxf(x, 0.0f) + log1pf(expf(-fabsf(x)));
}

// ---------------------------------------------------------------------------
// K1: aq = softplus(query@Wa+ba), rq = softplus(query@Wr+br); also rq_t[b][a][h]
// grid (32, 4), block 256. Each block: 2 consecutive b, 256 of the 1024 cols
// (cols 0..511 -> aq, 512..1023 -> rq). W reads coalesced; q reads scalar.
// ---------------------------------------------------------------------------
__global__ __launch_bounds__(256) void k_proj(
    const float* __restrict__ q, const float* __restrict__ Wa,
    const float* __restrict__ ba, const float* __restrict__ Wr,
    const float* __restrict__ br, float* __restrict__ aq,
    float* __restrict__ rq, float* __restrict__ rq_t) {
    const int bg = blockIdx.x;          // 0..31 -> b0=2bg, b1=2bg+1
    const int c  = blockIdx.y * 256 + threadIdx.x;   // 0..1023
    const int b0 = bg * 2, b1 = b0 + 1;

    const float* W; const float* bias; int col;
    if (c < 512) { W = Wa; bias = ba; col = c; }
    else         { W = Wr; bias = br; col = c - 512; }

    float a0 = bias[col];
    float a1 = a0;
    const float* q0 = q + (size_t)b0 * DMODEL;
    const float* q1 = q + (size_t)b1 * DMODEL;
    #pragma unroll 8
    for (int k = 0; k < DMODEL; ++k) {
        float wv = W[(size_t)k * 512 + col];
        a0 = fmaf(q0[k], wv, a0);
        a1 = fmaf(q1[k], wv, a1);
    }
    float s0 = softplusf(a0);
    float s1 = softplusf(a1);
    if (c < 512) {
        aq[b0 * 512 + col] = s0;
        aq[b1 * 512 + col] = s1;
    } else {
        rq[b0 * 512 + col] = s0;
        rq[b1 * 512 + col] = s1;
        int h = col >> 6, a = col & 63;
        rq_t[(b0 * DADDR + a) * H_ + h] = s0;
        rq_t[(b1 * DADDR + a) * H_ + h] = s1;
    }
}

// ---------------------------------------------------------------------------
// K2: per b: k=softplus(addresses) (in LDS), w[h,m], r2[h,m], den1, den2,
//     scale[b,h] = 1/(den1*den2). wtab stored [b][m][h] for scalar loads.
// grid 64, block 256.
// ---------------------------------------------------------------------------
__global__ __launch_bounds__(256) void k_coef(
    const float* __restrict__ addresses, const float* __restrict__ normalizer,
    const float* __restrict__ aq, const float* __restrict__ rq,
    float* __restrict__ wtab, float* __restrict__ scale) {
    __shared__ float ks[M_ * DADDR];          // 32 KB
    __shared__ float aqs[H_ * DADDR];         // 2 KB
    __shared__ float rqs[H_ * DADDR];         // 2 KB
    __shared__ float ws[H_ * M_];             // 4 KB
    __shared__ float r2s[H_ * M_];            // 4 KB

    const int b = blockIdx.x, tid = threadIdx.x;

    for (int i = tid; i < M_ * DADDR; i += 256) {
        ks[i] = softplusf(addresses[i]);
    }
    for (int i = tid; i < H_ * DADDR; i += 256) {
        aqs[i] = aq[b * 512 + i];
        rqs[i] = rq[b * 512 + i];
    }
    __syncthreads();

    for (int i = tid; i < H_ * M_; i += 256) {
        int m = i & (M_ - 1), h = i >> 7;
        const float4* a4 = (const float4*)(aqs + h * DADDR);
        const float4* r4 = (const float4*)(rqs + h * DADDR);
        const float4* k4 = (const float4*)(ks + m * DADDR);
        const float4* n4 = (const float4*)(normalizer + ((size_t)b * M_ + m) * DADDR);
        float w = 0.f, r2 = 0.f;
        #pragma unroll 4
        for (int a = 0; a < DADDR / 4; ++a) {
            float4 av = a4[a], kv = k4[a], rv = r4[a], nv = n4[a];
            w  = fmaf(av.x, kv.x, fmaf(av.y, kv.y, fmaf(av.z, kv.z, fmaf(av.w, kv.w, w))));
            r2 = fmaf(rv.x, nv.x, fmaf(rv.y, nv.y, fmaf(rv.z, nv.z, fmaf(rv.w, nv.w, r2))));
        }
        ws[h * M_ + m]  = w;
        r2s[h * M_ + m] = r2;
        wtab[((size_t)b * M_ + m) * H_ + h] = w;
    }
    __syncthreads();

    if (tid < H_) {
        int h = tid;
        float d1 = EPSF, dn = 0.f;
        for (int m = 0; m < M_; ++m) {
            d1 += ws[h * M_ + m];
            dn = fmaf(ws[h * M_ + m], r2s[h * M_ + m], dn);
        }
        float den2 = dn / d1 + EPSF;
        scale[b * H_ + h] = 1.0f / (d1 * den2);
    }
}

// ---------------------------------------------------------------------------
// K4 (heavy, memory-bound): num_raw[b,h,d] += w[b,h,m]*rq[b,h,a]*matrix[b,m,a,d]
// grid (64, 16), block 256 = 4 waves; each wave owns 2 m-rows; lanes = d-pairs.
// Per-m accumulator t[h] contracts over a with rq from scalar loads; the
// w[h,m] fold happens once per row. Partials atomicAdd'd into gnum.
// ---------------------------------------------------------------------------
__global__ __launch_bounds__(256) void k_heavy(
    const float* __restrict__ matrix, const float* __restrict__ wtab,
    const float* __restrict__ rq_t, float* __restrict__ gnum) {
    const int b    = blockIdx.x;
    const int chnk = blockIdx.y;             // 16 chunks of 8 m
    const int wave = threadIdx.x >> 6;
    const int lane = threadIdx.x & 63;

    float acc[H_][2];
    #pragma unroll
    for (int h = 0; h < H_; ++h) { acc[h][0] = 0.f; acc[h][1] = 0.f; }

    const float* __restrict__ rqt = rq_t + (size_t)b * DADDR * H_;

    #pragma unroll
    for (int mi = 0; mi < 2; ++mi) {
        const int m = __builtin_amdgcn_readfirstlane(chnk * 8 + wave * 2 + mi);
        const float* __restrict__ row =
            matrix + ((size_t)(b * M_ + m)) * (DADDR * DMEM) + lane * 2;

        float t[H_][2];
        #pragma unroll
        for (int h = 0; h < H_; ++h) { t[h][0] = 0.f; t[h][1] = 0.f; }

        #pragma unroll 4
        for (int a = 0; a < DADDR; ++a) {
            float2 v = *(const float2*)(row + (size_t)a * DMEM);
            const float* __restrict__ r8 = rqt + a * H_;
            #pragma unroll
            for (int h = 0; h < H_; ++h) {
                t[h][0] = fmaf(r8[h], v.x, t[h][0]);
                t[h][1] = fmaf(r8[h], v.y, t[h][1]);
            }
        }
        const float* __restrict__ w8 = wtab + ((size_t)b * M_ + m) * H_;
        #pragma unroll
        for (int h = 0; h < H_; ++h) {
            acc[h][0] = fmaf(w8[h], t[h][0], acc[h][0]);
            acc[h][1] = fmaf(w8[h], t[h][1], acc[h][1]);
        }
    }

    float* g = gnum + (size_t)b * (H_ * DMEM) + lane * 2;
    #pragma unroll
    for (int h = 0; h < H_; ++h) {
        atomicAdd(g + h * DMEM + 0, acc[h][0]);
        atomicAdd(g + h * DMEM + 1, acc[h][1]);
    }
}

// ---------------------------------------------------------------------------
// K5: out[b][j] = bm[j] + sum_h scale[b,h] * sum_{i in h-block} gnum[b,i]*Wm[i,j]
// grid (32, 4), block 256: 2 b per block, 256 j per block. Wm coalesced,
// gnum/scale via scalar loads.
// ---------------------------------------------------------------------------
__global__ __launch_bounds__(256) void k_out(
    const float* __restrict__ gnum, const float* __restrict__ scale,
    const float* __restrict__ Wm, const float* __restrict__ bm,
    float* __restrict__ out) {
    const int bg = blockIdx.x;
    const int j  = blockIdx.y * 256 + threadIdx.x;   // 0..1023
    const int b0 = bg * 2, b1 = b0 + 1;

    float o0 = bm[j], o1 = o0;
    const float* g0 = gnum + (size_t)b0 * DMODEL;
    const float* g1 = gnum + (size_t)b1 * DMODEL;

    for (int h = 0; h < H_; ++h) {
        float p0 = 0.f, p1 = 0.f;
        #pragma unroll 8
        for (int ii = 0; ii < DMEM; ++ii) {
            int i = h * DMEM + ii;
            float wv = Wm[(size_t)i * DMODEL + j];
            p0 = fmaf(g0[i], wv, p0);
            p1 = fmaf(g1[i], wv, p1);
        }
        o0 = fmaf(scale[b0 * H_ + h], p0, o0);
        o1 = fmaf(scale[b1 * H_ + h], p1, o1);
    }
    out[(size_t)b0 * DMODEL + j] = o0;
    out[(size_t)b1 * DMODEL + j] = o1;
}

// ---------------------------------------------------------------------------
extern "C" void kernel_launch(void* const* d_in, const int* in_sizes, int n_in,
                              void* d_out, int out_size, void* d_ws, size_t ws_size,
                              hipStream_t stream) {
    const float* query      = (const float*)d_in[0];
    const float* addresses  = (const float*)d_in[1];
    const float* matrix     = (const float*)d_in[2];
    const float* normalizer = (const float*)d_in[3];
    const float* Wa         = (const float*)d_in[4];
    const float* ba         = (const float*)d_in[5];
    const float* Wr         = (const float*)d_in[6];
    const float* br         = (const float*)d_in[7];
    const float* Wm         = (const float*)d_in[8];
    const float* bm         = (const float*)d_in[9];
    float* out = (float*)d_out;

    // workspace carve-up (floats), all 256B-aligned
    float* ws    = (float*)d_ws;
    float* aq    = ws;                 // 64*512   = 32768
    float* rq    = ws + 32768;         // 32768
    float* rq_t  = ws + 65536;         // 32768 ([b][a][h])
    float* wtab  = ws + 98304;         // 64*128*8 = 65536 ([b][m][h])
    float* scale = ws + 163840;        // 512
    float* gnum  = ws + 164352;        // 64*1024  = 65536

    hipMemsetAsync(gnum, 0, (size_t)B_ * DMODEL * sizeof(float), stream);

    k_proj<<<dim3(32, 4), 256, 0, stream>>>(query, Wa, ba, Wr, br, aq, rq, rq_t);
    k_coef<<<dim3(64), 256, 0, stream>>>(addresses, normalizer, aq, rq, wtab, scale);
    k_heavy<<<dim3(64, 16), 256, 0, stream>>>(matrix, wtab, rq_t, gnum);
    k_out<<<dim3(32, 4), 256, 0, stream>>>(gnum, scale, Wm, bm, out);
}